// Round 5
// baseline (166.311 us; speedup 1.0000x reference)
//
#include <hip/hip_runtime.h>
#include <hip/hip_bf16.h>
#include <math.h>

typedef __attribute__((ext_vector_type(8))) short short8;
typedef __attribute__((ext_vector_type(4))) float f32x4;

#define S_LEN   2048
#define DMODEL  1024
#define NHEAD   16
#define HDK     64
#define NBATCH  2
#define MTOT    (NBATCH*S_LEN)   // 4096
#define LOG2E   1.4426950408889634f

__device__ __forceinline__ unsigned short f2bf(float f) {
  union { float f; unsigned u; } c; c.f = f;
  unsigned r = c.u + 0x7FFFu + ((c.u >> 16) & 1u);
  return (unsigned short)(r >> 16);
}

__device__ __forceinline__ short8 lds_ld16(const unsigned short* p) {
  return *reinterpret_cast<const short8*>(p);   // 16B-aligned LDS read
}

__device__ __forceinline__ void gload_lds16(const unsigned short* g, unsigned short* l) {
  __builtin_amdgcn_global_load_lds(
      (const __attribute__((address_space(1))) unsigned int*)g,
      (__attribute__((address_space(3))) unsigned int*)l, 16, 0, 0);
}

// ---------- weight transpose + bf16 convert: w[k][n] f32 -> wt[n][k] bf16 ----------
__global__ __launch_bounds__(256) void transpose_w_kernel(
    const float* __restrict__ qw, const float* __restrict__ kw,
    const float* __restrict__ vw, const float* __restrict__ ow,
    unsigned short* __restrict__ wqkv, unsigned short* __restrict__ wo) {
  int z = blockIdx.z;
  const float* src = (z==0)?qw:(z==1)?kw:(z==2)?vw:ow;
  unsigned short* dst = (z<3) ? (wqkv + (size_t)z*DMODEL*DMODEL) : wo;
  __shared__ float tile[32][33];
  int n0 = blockIdx.x*32, k0 = blockIdx.y*32;
  int tx = threadIdx.x, ty = threadIdx.y;
  for (int r = ty; r < 32; r += 8)
    tile[r][tx] = src[(size_t)(k0+r)*DMODEL + n0 + tx];
  __syncthreads();
  for (int r = ty; r < 32; r += 8)
    dst[(size_t)(n0+r)*DMODEL + k0 + tx] = f2bf(tile[tx][r]);
}

// ---------- relative-position bias table: btab[h][rel+2047], pre-scaled by log2e ----------
__global__ void bias_table_kernel(const float* __restrict__ rel_emb,
                                  float* __restrict__ btab) {
  int idx = blockIdx.x*256 + threadIdx.x;
  if (idx >= NHEAD*4095) return;
  int h = idx / 4095, rp = idx % 4095, rel = rp - 2047;
  int bucket = (rel > 0) ? 16 : 0;
  int n = (rel < 0) ? -rel : rel;
  int v;
  if (n < 8) v = n;
  else {
    float lrv = logf((float)n * 0.125f) / 2.7725887f * 8.0f;  // log(n/8)/log(16)*8
    v = 8 + (int)lrv;
    if (v > 15) v = 15;
  }
  btab[idx] = rel_emb[(size_t)(bucket + v)*NHEAD + h] * LOG2E;
}

// ---------- RMSNorm -> bf16 ----------
__global__ __launch_bounds__(256) void rmsnorm_kernel(
    const float* __restrict__ hs, const float* __restrict__ lnw,
    unsigned short* __restrict__ xo) {
  int row = blockIdx.x, t = threadIdx.x;
  const float4 v = ((const float4*)(hs + (size_t)row*DMODEL))[t];
  float ss = v.x*v.x + v.y*v.y + v.z*v.z + v.w*v.w;
  #pragma unroll
  for (int off = 32; off >= 1; off >>= 1) ss += __shfl_xor(ss, off, 64);
  __shared__ float wsum[4];
  if ((t & 63) == 0) wsum[t >> 6] = ss;
  __syncthreads();
  float tot = wsum[0] + wsum[1] + wsum[2] + wsum[3];
  float sc = rsqrtf(tot * (1.0f/DMODEL) + 1e-6f);
  const float4 lw = ((const float4*)lnw)[t];
  uint2 o;
  o.x = (unsigned)f2bf(v.x*sc*lw.x) | ((unsigned)f2bf(v.y*sc*lw.y) << 16);
  o.y = (unsigned)f2bf(v.z*sc*lw.z) | ((unsigned)f2bf(v.w*sc*lw.w) << 16);
  ((uint2*)(xo + (size_t)row*DMODEL))[t] = o;
}

// ---------- 128x128 tile MFMA GEMM, BK=64, swizzled staging ----------
// EPI=0: write bf16 q/k in [B*H][S][64] (z: 0=q *log2e, 1=k)
// EPI=1: write f32 Of = resid + acc
// EPI=2: A=WvT, Bt=x -> write bf16 V^T in [B][1024][S]
template<int EPI>
__global__ __launch_bounds__(256) void gemm128(
    const unsigned short* __restrict__ A,
    const unsigned short* __restrict__ Bt,
    unsigned short* __restrict__ Oq, unsigned short* __restrict__ Ok,
    unsigned short* __restrict__ Ov,
    const float* __restrict__ resid, float* __restrict__ Of) {
  __shared__ unsigned short As[128*64];   // [row][granule ^ (row&7)], linear dest
  __shared__ unsigned short Bs[128*64];
  const int m0 = blockIdx.x*128, n0 = blockIdx.y*128;
  const unsigned short* Bz = Bt + ((EPI==0) ? (size_t)blockIdx.z*DMODEL*DMODEL : 0);
  const int t = threadIdx.x, lane = t & 63, w = t >> 6;
  const int g = lane >> 4, lr = lane & 15;
  const int wr = (w >> 1)*64, wc = (w & 1)*64;

  f32x4 acc[4][4];
  #pragma unroll
  for (int mi = 0; mi < 4; mi++)
    #pragma unroll
    for (int ni = 0; ni < 4; ni++) acc[mi][ni] = (f32x4){0.f,0.f,0.f,0.f};

  // staging: 4 slots/thread/array; slot -> row=slot>>3, granule c8=slot&7,
  // source column pre-swizzled by row&7 (involution; read applies same XOR)
  const unsigned short* ag[4]; const unsigned short* bg[4];
  unsigned short* al[4]; unsigned short* bl[4];
  #pragma unroll
  for (int i = 0; i < 4; i++) {
    int slot = t + i*256, row = slot >> 3, c8 = slot & 7;
    int cs = c8 ^ (row & 7);
    ag[i] = A  + (size_t)(m0 + row)*DMODEL + cs*8;
    bg[i] = Bz + (size_t)(n0 + row)*DMODEL + cs*8;
    al[i] = As + slot*8;
    bl[i] = Bs + slot*8;
  }

  for (int kk = 0; kk < DMODEL; kk += 64) {
    #pragma unroll
    for (int i = 0; i < 4; i++) {
      gload_lds16(ag[i] + kk, al[i]);
      gload_lds16(bg[i] + kk, bl[i]);
    }
    __syncthreads();            // drains vmcnt -> tile staged
    #pragma unroll
    for (int ks = 0; ks < 2; ks++) {
      short8 af[4], bfr[4];
      #pragma unroll
      for (int mi = 0; mi < 4; mi++) {
        int R = wr + mi*16 + lr;
        af[mi] = lds_ld16(As + R*64 + (((ks*4 + g) ^ (R & 7)) << 3));
      }
      #pragma unroll
      for (int ni = 0; ni < 4; ni++) {
        int R = wc + ni*16 + lr;
        bfr[ni] = lds_ld16(Bs + R*64 + (((ks*4 + g) ^ (R & 7)) << 3));
      }
      #pragma unroll
      for (int mi = 0; mi < 4; mi++)
        #pragma unroll
        for (int ni = 0; ni < 4; ni++)
          acc[mi][ni] = __builtin_amdgcn_mfma_f32_16x16x32_bf16(af[mi], bfr[ni], acc[mi][ni], 0, 0, 0);
    }
    __syncthreads();            // reads done before next stage
  }

  if (EPI == 0) {
    unsigned short* dst = (blockIdx.z == 0) ? Oq : Ok;
    const float osc = (blockIdx.z == 0) ? LOG2E : 1.0f;
    #pragma unroll
    for (int mi = 0; mi < 4; mi++) {
      #pragma unroll
      for (int r = 0; r < 4; r++) {
        int m = m0 + wr + mi*16 + g*4 + r;
        int b = m >> 11, s = m & (S_LEN-1);
        unsigned short* drow = dst + ((size_t)b*NHEAD*S_LEN + s)*HDK;
        #pragma unroll
        for (int ni = 0; ni < 4; ni++) {
          int n = n0 + wc + ni*16 + lr;
          int h = n >> 6, dcol = n & 63;
          drow[(size_t)h*S_LEN*HDK + dcol] = f2bf(acc[mi][ni][r] * osc);
        }
      }
    }
  } else if (EPI == 2) {
    #pragma unroll
    for (int ni = 0; ni < 4; ni++) {
      int n = n0 + wc + ni*16 + lr;
      int b = n >> 11, s = n & (S_LEN-1);
      #pragma unroll
      for (int mi = 0; mi < 4; mi++)
        #pragma unroll
        for (int r = 0; r < 4; r++) {
          int m = m0 + wr + mi*16 + g*4 + r;
          Ov[((size_t)b*DMODEL + m)*S_LEN + s] = f2bf(acc[mi][ni][r]);
        }
    }
  } else {
    #pragma unroll
    for (int mi = 0; mi < 4; mi++) {
      #pragma unroll
      for (int r = 0; r < 4; r++) {
        int m = m0 + wr + mi*16 + g*4 + r;
        const float* rrow = resid + (size_t)m*DMODEL;
        float* orow = Of + (size_t)m*DMODEL;
        #pragma unroll
        for (int ni = 0; ni < 4; ni++) {
          int n = n0 + wc + ni*16 + lr;
          orow[n] = rrow[n] + acc[mi][ni][r];
        }
      }
    }
  }
}

// ---------- flash attention, swapped-QK^T, softmax1, exp2 domain ----------
// grid 512 flat (XCD-remapped), block 512 (8 waves x 16 q-rows), qblk=128
__global__ __launch_bounds__(512, 4) void attn_kernel(
    const unsigned short* __restrict__ Qg,
    const unsigned short* __restrict__ Kg,
    const unsigned short* __restrict__ Vtg,
    const float* __restrict__ btab,
    const float* __restrict__ gmask,
    unsigned short* __restrict__ Og) {
  __shared__ __align__(16) unsigned short Kl[2][64][64];   // [buf][key][d-gran ^ key&7]
  __shared__ __align__(16) unsigned short Vl[2][64][64];   // [buf][d][key-gran ^ d&7]
  __shared__ __align__(16) unsigned short Pl[8][16*64];    // per-wave P
  __shared__ __align__(16) float gl[S_LEN];                // gate*log2e

  // bijective XCD remap: 512 blocks = 8 XCDs x 64; each XCD owns 4 bh's
  const int flat = blockIdx.x + (int)gridDim.x*blockIdx.y;
  const int xcd = flat & 7, j = flat >> 3;
  const int bh = xcd*4 + (j >> 4), qx = j & 15;
  const int b = bh >> 4, h = bh & 15;
  const int q0 = qx * 128;

  const int t = threadIdx.x, w = t >> 6, lane = t & 63;
  const int g = lane >> 4, lr = lane & 15, l7 = lane & 7;
  const int srow = t >> 3, sg0 = t & 7;
  const int swz = (sg0 ^ (srow & 7)) << 3;

  const unsigned short* Qb = Qg  + (size_t)bh*S_LEN*HDK;
  const unsigned short* Kb = Kg  + (size_t)bh*S_LEN*HDK;
  const unsigned short* Vb = Vtg + (size_t)bh*HDK*S_LEN;   // [d][s]

  // stage gate (scaled) once: 512 threads x 1 float4
  {
    float4 gv = ((const float4*)(gmask + (size_t)b*S_LEN))[t];
    float4 gs; gs.x = gv.x*LOG2E; gs.y = gv.y*LOG2E; gs.z = gv.z*LOG2E; gs.w = gv.w*LOG2E;
    ((float4*)gl)[t] = gs;
  }

  // Q fragments: wave owns 16 q-rows
  const int qs0 = q0 + w*16;
  short8 qf0 = *reinterpret_cast<const short8*>(Qb + (size_t)(qs0+lr)*HDK + g*8);
  short8 qf1 = *reinterpret_cast<const short8*>(Qb + (size_t)(qs0+lr)*HDK + 32 + g*8);

  f32x4 acc[4];
  #pragma unroll
  for (int n = 0; n < 4; n++) acc[n] = (f32x4){0.f,0.f,0.f,0.f};
  float mr = -1e30f, lsum = 0.f;   // per-lane: q = lr (replicated x4 groups)

  const float* btb = btab + (size_t)h*4095 + 2047;
  const float cpos = btb[91];    // bucket saturates for |rel| >= 91
  const float cneg = btb[-91];

  // prologue: stage tile 0 (one uint4 per thread per array)
  {
    *reinterpret_cast<uint4*>(&Kl[0][srow][swz]) =
        *reinterpret_cast<const uint4*>(Kb + (size_t)srow*HDK + sg0*8);
    *reinterpret_cast<uint4*>(&Vl[0][srow][swz]) =
        *reinterpret_cast<const uint4*>(Vb + (size_t)srow*S_LEN + sg0*8);
  }

  char* prow = (char*)&Pl[w][0] + lr*128;   // this lane's P row (q = lr)

  int cur = 0;
  const int NT = S_LEN/64;
  for (int kt = 0; kt < NT; ++kt) {
    const int key0 = kt*64;
    __syncthreads();   // buf[cur] staged; all reads of buf[cur^1] done

    uint4 nk, nv;
    const bool pf = (kt + 1 < NT);
    if (pf) {
      nk = *reinterpret_cast<const uint4*>(Kb + (size_t)(key0+64+srow)*HDK + sg0*8);
      nv = *reinterpret_cast<const uint4*>(Vb + (size_t)srow*S_LEN + key0+64 + sg0*8);
    }

    // K fragments (A-frag: row=key=n*16+lr, k=d)
    short8 bk[4][2];
    #pragma unroll
    for (int n = 0; n < 4; n++) {
      const unsigned short* kr = &Kl[cur][n*16 + lr][0];
      bk[n][0] = lds_ld16(kr + ((g ^ l7) << 3));
      bk[n][1] = lds_ld16(kr + (((4 + g) ^ l7) << 3));
    }
    // V fragments (B-frag: k=key, col=d=n*16+lr)
    short8 bv[2][4];
    #pragma unroll
    for (int c = 0; c < 2; c++)
      #pragma unroll
      for (int n = 0; n < 4; n++)
        bv[c][n] = lds_ld16(&Vl[cur][n*16 + lr][((4*c + g) ^ l7) << 3]);
    // gate quads (LDS broadcast)
    float4 gq[4];
    #pragma unroll
    for (int n = 0; n < 4; n++) gq[n] = *(const float4*)&gl[key0 + n*16 + g*4];

    // S^T = K Q^T: lane holds q=lr, keys key0 + n*16 + g*4 + r
    float s[4][4];
    #pragma unroll
    for (int n = 0; n < 4; n++) {
      f32x4 z = (f32x4){0.f,0.f,0.f,0.f};
      f32x4 sv = __builtin_amdgcn_mfma_f32_16x16x32_bf16(bk[n][0], qf0, z, 0, 0, 0);
      sv = __builtin_amdgcn_mfma_f32_16x16x32_bf16(bk[n][1], qf1, sv, 0, 0, 0);
      #pragma unroll
      for (int r = 0; r < 4; r++) s[n][r] = sv[r];
    }

    // bias + gate (log2 domain)
    const int dband = key0 - qs0;
    if (dband > -154 && dband < 106) {
      const float* btq = btb + (dband - lr);
      #pragma unroll
      for (int n = 0; n < 4; n++)
        #pragma unroll
        for (int r = 0; r < 4; r++)
          s[n][r] += gq[n][r] + btq[n*16 + g*4 + r];
    } else {
      const float cc = (dband > 0) ? cpos : cneg;
      #pragma unroll
      for (int n = 0; n < 4; n++)
        #pragma unroll
        for (int r = 0; r < 4; r++)
          s[n][r] += gq[n][r] + cc;
    }

    // online softmax, defer-max
    float pmax = s[0][0];
    #pragma unroll
    for (int n = 0; n < 4; n++)
      #pragma unroll
      for (int r = 0; r < 4; r++) pmax = fmaxf(pmax, s[n][r]);
    if (__any(pmax > mr + 8.0f)) {
      float tm = pmax;
      tm = fmaxf(tm, __shfl_xor(tm, 16));
      tm = fmaxf(tm, __shfl_xor(tm, 32));
      float mnew = fmaxf(mr, tm);
      float scv = exp2f(mr - mnew);
      mr = mnew; lsum *= scv;
      #pragma unroll
      for (int r = 0; r < 4; r++) {
        float s4 = __shfl(scv, g*4 + r, 16);
        #pragma unroll
        for (int n = 0; n < 4; n++) acc[n][r] *= s4;
      }
    }
    #pragma unroll
    for (int n = 0; n < 4; n++)
      #pragma unroll
      for (int r = 0; r < 4; r++) {
        float p = exp2f(s[n][r] - mr);
        s[n][r] = p; lsum += p;
      }

    // P -> per-wave LDS (cvt_pk packed, swizzled)
    #pragma unroll
    for (int n = 0; n < 4; n++) {
      unsigned plo, phi;
      asm("v_cvt_pk_bf16_f32 %0, %1, %2" : "=v"(plo) : "v"(s[n][0]), "v"(s[n][1]));
      asm("v_cvt_pk_bf16_f32 %0, %1, %2" : "=v"(phi) : "v"(s[n][2]), "v"(s[n][3]));
      uint2 pw; pw.x = plo; pw.y = phi;
      *reinterpret_cast<uint2*>(prow + ((((2*n + (g>>1)) ^ l7) << 4) + ((g & 1) << 3))) = pw;
    }
    // no barrier: Pl[w] wave-private; lgkmcnt orders write->read

    // O += P V
    #pragma unroll
    for (int c = 0; c < 2; c++) {
      short8 pa = lds_ld16((const unsigned short*)(prow + (((4*c + g) ^ l7) << 4)));
      #pragma unroll
      for (int n = 0; n < 4; n++)
        acc[n] = __builtin_amdgcn_mfma_f32_16x16x32_bf16(pa, bv[c][n], acc[n], 0, 0, 0);
    }

    // write next tile into the other buffer
    if (pf) {
      *reinterpret_cast<uint4*>(&Kl[cur^1][srow][swz]) = nk;
      *reinterpret_cast<uint4*>(&Vl[cur^1][srow][swz]) = nv;
    }
    cur ^= 1;
  }

  // finalize: softmax1 denom = l + 2^(-m)
  {
    float rs = lsum;
    rs += __shfl_xor(rs, 16);
    rs += __shfl_xor(rs, 32);
    float inv = 1.0f / (rs + exp2f(-mr));
    #pragma unroll
    for (int r = 0; r < 4; r++) {
      float inv4 = __shfl(inv, g*4 + r, 16);
      int srw = qs0 + g*4 + r;
      unsigned short* orow = Og + ((size_t)b*S_LEN + srw)*DMODEL + h*HDK;
      #pragma unroll
      for (int n = 0; n < 4; n++)
        orow[n*16 + lr] = f2bf(acc[n][r] * inv4);
    }
  }
}

extern "C" void kernel_launch(void* const* d_in, const int* in_sizes, int n_in,
                              void* d_out, int out_size, void* d_ws, size_t ws_size,
                              hipStream_t stream) {
  const float* hs   = (const float*)d_in[0];
  const float* gate = (const float*)d_in[1];
  const float* lnw  = (const float*)d_in[2];
  const float* qw   = (const float*)d_in[3];
  const float* kw   = (const float*)d_in[4];
  const float* vw   = (const float*)d_in[5];
  const float* ow   = (const float*)d_in[6];
  const float* rel  = (const float*)d_in[7];
  float* out = (float*)d_out;

  char* ws = (char*)d_ws;
  const size_t MB = 1ull << 20;
  unsigned short* xbf  = (unsigned short*)(ws);            // 8 MB  x (bf16)
  unsigned short* wqkv = (unsigned short*)(ws + 8*MB);     // 6 MB  q/k/v weights^T
  unsigned short* wo   = (unsigned short*)(ws + 14*MB);    // 2 MB  o weight^T
  unsigned short* qb   = (unsigned short*)(ws + 16*MB);    // 8 MB  q [BH][S][64] (log2e-scaled)
  unsigned short* kb   = (unsigned short*)(ws + 24*MB);    // 8 MB  k [BH][S][64]
  unsigned short* vt   = (unsigned short*)(ws + 32*MB);    // 8 MB  v^T [B][1024][S]
  unsigned short* ao   = (unsigned short*)(ws + 40*MB);    // 8 MB  attn_out [B][S][1024]
  float*          btab = (float*)(ws + 48*MB);             // 256 KB bias table (log2e-scaled)

  transpose_w_kernel<<<dim3(32,32,4), dim3(32,8), 0, stream>>>(qw, kw, vw, ow, wqkv, wo);
  bias_table_kernel<<<dim3(256), dim3(256), 0, stream>>>(rel, btab);
  rmsnorm_kernel<<<dim3(MTOT), dim3(256), 0, stream>>>(hs, lnw, xbf);
  gemm128<0><<<dim3(MTOT/128, DMODEL/128, 2), dim3(256), 0, stream>>>(
      xbf, wqkv, qb, kb, nullptr, nullptr, nullptr);
  gemm128<2><<<dim3(DMODEL/128, MTOT/128, 1), dim3(256), 0, stream>>>(
      wqkv + (size_t)2*DMODEL*DMODEL, xbf, nullptr, nullptr, vt, nullptr, nullptr);
  attn_kernel<<<dim3(S_LEN/128, NBATCH*NHEAD), dim3(512), 0, stream>>>(
      qb, kb, vt, btab, gate, ao);
  gemm128<1><<<dim3(MTOT/128, DMODEL/128, 1), dim3(256), 0, stream>>>(
      ao, wo, nullptr, nullptr, nullptr, hs, out);
}

// Round 6
// 154.702 us; speedup vs baseline: 1.0750x; 1.0750x over previous
//
#include <hip/hip_runtime.h>
#include <hip/hip_bf16.h>
#include <math.h>

typedef __attribute__((ext_vector_type(8))) short short8;
typedef __attribute__((ext_vector_type(4))) float f32x4;

#define S_LEN   2048
#define DMODEL  1024
#define NHEAD   16
#define HDK     64
#define NBATCH  2
#define MTOT    (NBATCH*S_LEN)   // 4096
#define LOG2E   1.4426950408889634f

__device__ __forceinline__ unsigned short f2bf(float f) {
  union { float f; unsigned u; } c; c.f = f;
  unsigned r = c.u + 0x7FFFu + ((c.u >> 16) & 1u);
  return (unsigned short)(r >> 16);
}

__device__ __forceinline__ short8 lds_ld16(const unsigned short* p) {
  return *reinterpret_cast<const short8*>(p);   // 16B-aligned LDS read
}

__device__ __forceinline__ void gload_lds16(const unsigned short* g, unsigned short* l) {
  __builtin_amdgcn_global_load_lds(
      (const __attribute__((address_space(1))) unsigned int*)g,
      (__attribute__((address_space(3))) unsigned int*)l, 16, 0, 0);
}

// ---------- weight transpose + bf16 convert: w[k][n] f32 -> wt[n][k] bf16 ----------
__global__ __launch_bounds__(256) void transpose_w_kernel(
    const float* __restrict__ qw, const float* __restrict__ kw,
    const float* __restrict__ vw, const float* __restrict__ ow,
    unsigned short* __restrict__ wqkv, unsigned short* __restrict__ wo) {
  int z = blockIdx.z;
  const float* src = (z==0)?qw:(z==1)?kw:(z==2)?vw:ow;
  unsigned short* dst = (z<3) ? (wqkv + (size_t)z*DMODEL*DMODEL) : wo;
  __shared__ float tile[32][33];
  int n0 = blockIdx.x*32, k0 = blockIdx.y*32;
  int tx = threadIdx.x, ty = threadIdx.y;
  for (int r = ty; r < 32; r += 8)
    tile[r][tx] = src[(size_t)(k0+r)*DMODEL + n0 + tx];
  __syncthreads();
  for (int r = ty; r < 32; r += 8)
    dst[(size_t)(n0+r)*DMODEL + k0 + tx] = f2bf(tile[tx][r]);
}

// ---------- relative-position bias table: btab[h][rel+2047], pre-scaled by log2e ----------
__global__ void bias_table_kernel(const float* __restrict__ rel_emb,
                                  float* __restrict__ btab) {
  int idx = blockIdx.x*256 + threadIdx.x;
  if (idx >= NHEAD*4095) return;
  int h = idx / 4095, rp = idx % 4095, rel = rp - 2047;
  int bucket = (rel > 0) ? 16 : 0;
  int n = (rel < 0) ? -rel : rel;
  int v;
  if (n < 8) v = n;
  else {
    float lrv = logf((float)n * 0.125f) / 2.7725887f * 8.0f;  // log(n/8)/log(16)*8
    v = 8 + (int)lrv;
    if (v > 15) v = 15;
  }
  btab[idx] = rel_emb[(size_t)(bucket + v)*NHEAD + h] * LOG2E;
}

// ---------- RMSNorm -> bf16 ----------
__global__ __launch_bounds__(256) void rmsnorm_kernel(
    const float* __restrict__ hs, const float* __restrict__ lnw,
    unsigned short* __restrict__ xo) {
  int row = blockIdx.x, t = threadIdx.x;
  const float4 v = ((const float4*)(hs + (size_t)row*DMODEL))[t];
  float ss = v.x*v.x + v.y*v.y + v.z*v.z + v.w*v.w;
  #pragma unroll
  for (int off = 32; off >= 1; off >>= 1) ss += __shfl_xor(ss, off, 64);
  __shared__ float wsum[4];
  if ((t & 63) == 0) wsum[t >> 6] = ss;
  __syncthreads();
  float tot = wsum[0] + wsum[1] + wsum[2] + wsum[3];
  float sc = rsqrtf(tot * (1.0f/DMODEL) + 1e-6f);
  const float4 lw = ((const float4*)lnw)[t];
  uint2 o;
  o.x = (unsigned)f2bf(v.x*sc*lw.x) | ((unsigned)f2bf(v.y*sc*lw.y) << 16);
  o.y = (unsigned)f2bf(v.z*sc*lw.z) | ((unsigned)f2bf(v.w*sc*lw.w) << 16);
  ((uint2*)(xo + (size_t)row*DMODEL))[t] = o;
}

// ---------- 128x128 tile MFMA GEMM, BK=64, swizzled staging ----------
template<int EPI>
__global__ __launch_bounds__(256) void gemm128(
    const unsigned short* __restrict__ A,
    const unsigned short* __restrict__ Bt,
    unsigned short* __restrict__ Oq, unsigned short* __restrict__ Ok,
    unsigned short* __restrict__ Ov,
    const float* __restrict__ resid, float* __restrict__ Of) {
  __shared__ unsigned short As[128*64];   // [row][granule ^ (row&7)], linear dest
  __shared__ unsigned short Bs[128*64];
  const int m0 = blockIdx.x*128, n0 = blockIdx.y*128;
  const unsigned short* Bz = Bt + ((EPI==0) ? (size_t)blockIdx.z*DMODEL*DMODEL : 0);
  const int t = threadIdx.x, lane = t & 63, w = t >> 6;
  const int g = lane >> 4, lr = lane & 15;
  const int wr = (w >> 1)*64, wc = (w & 1)*64;

  f32x4 acc[4][4];
  #pragma unroll
  for (int mi = 0; mi < 4; mi++)
    #pragma unroll
    for (int ni = 0; ni < 4; ni++) acc[mi][ni] = (f32x4){0.f,0.f,0.f,0.f};

  const unsigned short* ag[4]; const unsigned short* bg[4];
  unsigned short* al[4]; unsigned short* bl[4];
  #pragma unroll
  for (int i = 0; i < 4; i++) {
    int slot = t + i*256, row = slot >> 3, c8 = slot & 7;
    int cs = c8 ^ (row & 7);
    ag[i] = A  + (size_t)(m0 + row)*DMODEL + cs*8;
    bg[i] = Bz + (size_t)(n0 + row)*DMODEL + cs*8;
    al[i] = As + slot*8;
    bl[i] = Bs + slot*8;
  }

  for (int kk = 0; kk < DMODEL; kk += 64) {
    #pragma unroll
    for (int i = 0; i < 4; i++) {
      gload_lds16(ag[i] + kk, al[i]);
      gload_lds16(bg[i] + kk, bl[i]);
    }
    __syncthreads();            // drains vmcnt -> tile staged
    #pragma unroll
    for (int ks = 0; ks < 2; ks++) {
      short8 af[4], bfr[4];
      #pragma unroll
      for (int mi = 0; mi < 4; mi++) {
        int R = wr + mi*16 + lr;
        af[mi] = lds_ld16(As + R*64 + (((ks*4 + g) ^ (R & 7)) << 3));
      }
      #pragma unroll
      for (int ni = 0; ni < 4; ni++) {
        int R = wc + ni*16 + lr;
        bfr[ni] = lds_ld16(Bs + R*64 + (((ks*4 + g) ^ (R & 7)) << 3));
      }
      #pragma unroll
      for (int mi = 0; mi < 4; mi++)
        #pragma unroll
        for (int ni = 0; ni < 4; ni++)
          acc[mi][ni] = __builtin_amdgcn_mfma_f32_16x16x32_bf16(af[mi], bfr[ni], acc[mi][ni], 0, 0, 0);
    }
    __syncthreads();            // reads done before next stage
  }

  if (EPI == 0) {
    unsigned short* dst = (blockIdx.z == 0) ? Oq : Ok;
    const float osc = (blockIdx.z == 0) ? LOG2E : 1.0f;
    #pragma unroll
    for (int mi = 0; mi < 4; mi++) {
      #pragma unroll
      for (int r = 0; r < 4; r++) {
        int m = m0 + wr + mi*16 + g*4 + r;
        int b = m >> 11, s = m & (S_LEN-1);
        unsigned short* drow = dst + ((size_t)b*NHEAD*S_LEN + s)*HDK;
        #pragma unroll
        for (int ni = 0; ni < 4; ni++) {
          int n = n0 + wc + ni*16 + lr;
          int h = n >> 6, dcol = n & 63;
          drow[(size_t)h*S_LEN*HDK + dcol] = f2bf(acc[mi][ni][r] * osc);
        }
      }
    }
  } else if (EPI == 2) {
    #pragma unroll
    for (int ni = 0; ni < 4; ni++) {
      int n = n0 + wc + ni*16 + lr;
      int b = n >> 11, s = n & (S_LEN-1);
      #pragma unroll
      for (int mi = 0; mi < 4; mi++)
        #pragma unroll
        for (int r = 0; r < 4; r++) {
          int m = m0 + wr + mi*16 + g*4 + r;
          Ov[((size_t)b*DMODEL + m)*S_LEN + s] = f2bf(acc[mi][ni][r]);
        }
    }
  } else {
    #pragma unroll
    for (int mi = 0; mi < 4; mi++) {
      #pragma unroll
      for (int r = 0; r < 4; r++) {
        int m = m0 + wr + mi*16 + g*4 + r;
        const float* rrow = resid + (size_t)m*DMODEL;
        float* orow = Of + (size_t)m*DMODEL;
        #pragma unroll
        for (int ni = 0; ni < 4; ni++) {
          int n = n0 + wc + ni*16 + lr;
          orow[n] = rrow[n] + acc[mi][ni][r];
        }
      }
    }
  }
}

// ---------- flash attention, swapped-QK^T layout, softmax1, exp2 domain ----------
// grid 512 flat (bijective XCD remap), block 256 (4 waves x 2 sets of 16 q-rows)
__global__ __launch_bounds__(256, 2) void attn_kernel(
    const unsigned short* __restrict__ Qg,
    const unsigned short* __restrict__ Kg,
    const unsigned short* __restrict__ Vtg,
    const float* __restrict__ btab,
    const float* __restrict__ gmask,
    unsigned short* __restrict__ Og) {
  __shared__ __align__(16) unsigned short Kl[2][64][64];   // [buf][key][d-granule ^ key&7]
  __shared__ __align__(16) unsigned short Vl[2][64][64];   // [buf][d][key-granule ^ d&7]
  __shared__ __align__(16) unsigned short Pl[4][16*64];    // per-wave P [q][key-gran ^ q&7]
  __shared__ __align__(16) float gl[S_LEN];                // gate*log2e for this batch

  // bijective XCD remap: 512 blocks = 8 XCDs x 64; each XCD owns 4 bh's
  const int flat = blockIdx.x;
  const int xcd = flat & 7, j = flat >> 3;
  const int bh = xcd*4 + (j >> 4), qx = j & 15;
  const int b = bh >> 4, h = bh & 15;
  const int q0 = qx * 128;

  const int t = threadIdx.x, w = t >> 6, lane = t & 63;
  const int g = lane >> 4, lr = lane & 15, l7 = lane & 7;
  const int srow0 = t >> 3, sg0 = t & 7, srow1 = srow0 + 32;
  const int swz = (sg0 ^ (srow0 & 7)) << 3;                // srow1&7 == srow0&7

  const unsigned short* Qb = Qg  + (size_t)bh*S_LEN*HDK;
  const unsigned short* Kb = Kg  + (size_t)bh*S_LEN*HDK;
  const unsigned short* Vb = Vtg + (size_t)bh*HDK*S_LEN;   // [d][s]

  // ---- stage gate (scaled) once ----
  {
    const float4* gm4 = (const float4*)(gmask + (size_t)b*S_LEN);
    #pragma unroll
    for (int i = 0; i < 2; i++) {
      int idx = t + i*256;
      float4 gv = gm4[idx];
      float4 gs; gs.x = gv.x*LOG2E; gs.y = gv.y*LOG2E; gs.z = gv.z*LOG2E; gs.w = gv.w*LOG2E;
      ((float4*)gl)[idx] = gs;
    }
  }

  // ---- Q fragments: wave owns q rows [q0+w*32, q0+w*32+32), two sets of 16 ----
  const int qs0A = q0 + w*32, qs0B = qs0A + 16;
  short8 qfA0 = *reinterpret_cast<const short8*>(Qb + (size_t)(qs0A+lr)*HDK + g*8);
  short8 qfA1 = *reinterpret_cast<const short8*>(Qb + (size_t)(qs0A+lr)*HDK + 32 + g*8);
  short8 qfB0 = *reinterpret_cast<const short8*>(Qb + (size_t)(qs0B+lr)*HDK + g*8);
  short8 qfB1 = *reinterpret_cast<const short8*>(Qb + (size_t)(qs0B+lr)*HDK + 32 + g*8);

  f32x4 accA[4], accB[4];
  #pragma unroll
  for (int n = 0; n < 4; n++) { accA[n] = (f32x4){0.f,0.f,0.f,0.f}; accB[n] = (f32x4){0.f,0.f,0.f,0.f}; }
  float mA = -1e30f, lA = 0.f, mB = -1e30f, lB = 0.f;  // per-lane: q = lr (replicated x4 groups)

  const float* btb = btab + (size_t)h*4095 + 2047;
  const float cpos = btb[91];    // bucket saturates for |rel| >= 91
  const float cneg = btb[-91];

  // ---- prologue: stage tile 0 ----
  {
    *reinterpret_cast<uint4*>(&Kl[0][srow0][swz]) =
        *reinterpret_cast<const uint4*>(Kb + (size_t)srow0*HDK + sg0*8);
    *reinterpret_cast<uint4*>(&Kl[0][srow1][swz]) =
        *reinterpret_cast<const uint4*>(Kb + (size_t)srow1*HDK + sg0*8);
    *reinterpret_cast<uint4*>(&Vl[0][srow0][swz]) =
        *reinterpret_cast<const uint4*>(Vb + (size_t)srow0*S_LEN + sg0*8);
    *reinterpret_cast<uint4*>(&Vl[0][srow1][swz]) =
        *reinterpret_cast<const uint4*>(Vb + (size_t)srow1*S_LEN + sg0*8);
  }

  char* prow = (char*)&Pl[w][0] + lr*128;   // this lane's P row (q = lr)

  int cur = 0;
  const int NT = S_LEN/64;
  for (int kt = 0; kt < NT; ++kt) {
    const int key0 = kt*64;
    __syncthreads();   // buf[cur] staged; all reads of buf[cur^1] done

    uint4 nk0, nk1, nv0, nv1;
    const bool pf = (kt + 1 < NT);
    if (pf) {
      nk0 = *reinterpret_cast<const uint4*>(Kb + (size_t)(key0+64+srow0)*HDK + sg0*8);
      nk1 = *reinterpret_cast<const uint4*>(Kb + (size_t)(key0+64+srow1)*HDK + sg0*8);
      nv0 = *reinterpret_cast<const uint4*>(Vb + (size_t)srow0*S_LEN + key0+64 + sg0*8);
      nv1 = *reinterpret_cast<const uint4*>(Vb + (size_t)srow1*S_LEN + key0+64 + sg0*8);
    }

    // ---- K fragments (A-frag: row=key=n*16+lr, k=d) ----
    short8 bk[4][2];
    #pragma unroll
    for (int n = 0; n < 4; n++) {
      const unsigned short* kr = &Kl[cur][n*16 + lr][0];
      bk[n][0] = lds_ld16(kr + ((g ^ l7) << 3));
      bk[n][1] = lds_ld16(kr + (((4 + g) ^ l7) << 3));
    }
    // ---- V fragments (B-frag: k=key, col=d=n*16+lr), shared by both sets ----
    short8 bv[2][4];
    #pragma unroll
    for (int c = 0; c < 2; c++)
      #pragma unroll
      for (int n = 0; n < 4; n++)
        bv[c][n] = lds_ld16(&Vl[cur][n*16 + lr][((4*c + g) ^ l7) << 3]);
    // ---- gate quads (broadcast reads) ----
    float4 gq[4];
    #pragma unroll
    for (int n = 0; n < 4; n++) gq[n] = *(const float4*)&gl[key0 + n*16 + g*4];

    // ---- S^T = K Q^T: lane holds q=lr, keys key0 + n*16 + g*4 + r ----
    f32x4 svA[4], svB[4];
    __builtin_amdgcn_s_setprio(1);
    #pragma unroll
    for (int n = 0; n < 4; n++) {
      f32x4 z = (f32x4){0.f,0.f,0.f,0.f};
      svA[n] = __builtin_amdgcn_mfma_f32_16x16x32_bf16(bk[n][0], qfA0, z, 0, 0, 0);
      svA[n] = __builtin_amdgcn_mfma_f32_16x16x32_bf16(bk[n][1], qfA1, svA[n], 0, 0, 0);
      svB[n] = __builtin_amdgcn_mfma_f32_16x16x32_bf16(bk[n][0], qfB0, z, 0, 0, 0);
      svB[n] = __builtin_amdgcn_mfma_f32_16x16x32_bf16(bk[n][1], qfB1, svB[n], 0, 0, 0);
    }
    __builtin_amdgcn_s_setprio(0);

#define PROCESS_SET(sv_, m_, l_, acc_, qs0_)                                          \
    {                                                                                 \
      float s_[4][4];                                                                 \
      _Pragma("unroll") for (int n = 0; n < 4; n++)                                   \
        _Pragma("unroll") for (int r = 0; r < 4; r++) s_[n][r] = sv_[n][r];           \
      const int dband = key0 - (qs0_);                                                \
      if (dband > -154 && dband < 106) {                                              \
        const float* btq = btb + (dband - lr);                                        \
        _Pragma("unroll") for (int n = 0; n < 4; n++)                                 \
          _Pragma("unroll") for (int r = 0; r < 4; r++)                               \
            s_[n][r] += gq[n][r] + btq[n*16 + g*4 + r];                               \
      } else {                                                                        \
        const float cc = (dband > 0) ? cpos : cneg;                                   \
        _Pragma("unroll") for (int n = 0; n < 4; n++)                                 \
          _Pragma("unroll") for (int r = 0; r < 4; r++)                               \
            s_[n][r] += gq[n][r] + cc;                                                \
      }                                                                               \
      float pmax = s_[0][0];                                                          \
      _Pragma("unroll") for (int n = 0; n < 4; n++)                                   \
        _Pragma("unroll") for (int r = 0; r < 4; r++) pmax = fmaxf(pmax, s_[n][r]);   \
      if (__any(pmax > m_ + 8.0f)) {                                                  \
        float tm = pmax;                                                              \
        tm = fmaxf(tm, __shfl_xor(tm, 16));                                           \
        tm = fmaxf(tm, __shfl_xor(tm, 32));                                           \
        float mnew = fmaxf(m_, tm);                                                   \
        float scv = exp2f(m_ - mnew);                                                 \
        m_ = mnew; l_ *= scv;                                                         \
        _Pragma("unroll") for (int r = 0; r < 4; r++) {                               \
          float s4 = __shfl(scv, g*4 + r, 16);                                        \
          _Pragma("unroll") for (int n = 0; n < 4; n++) acc_[n][r] *= s4;             \
        }                                                                             \
      }                                                                               \
      _Pragma("unroll") for (int n = 0; n < 4; n++)                                   \
        _Pragma("unroll") for (int r = 0; r < 4; r++) {                               \
          float p = exp2f(s_[n][r] - m_);                                             \
          s_[n][r] = p; l_ += p;                                                      \
        }                                                                             \
      _Pragma("unroll") for (int n = 0; n < 4; n++) {                                 \
        unsigned plo_, phi_;                                                          \
        asm("v_cvt_pk_bf16_f32 %0, %1, %2" : "=v"(plo_) : "v"(s_[n][0]), "v"(s_[n][1])); \
        asm("v_cvt_pk_bf16_f32 %0, %1, %2" : "=v"(phi_) : "v"(s_[n][2]), "v"(s_[n][3])); \
        uint2 pw_; pw_.x = plo_; pw_.y = phi_;                                        \
        *reinterpret_cast<uint2*>(prow + ((((2*n + (g>>1)) ^ l7) << 4) + ((g & 1) << 3))) = pw_; \
      }                                                                               \
      __builtin_amdgcn_s_setprio(1);                                                  \
      _Pragma("unroll") for (int c = 0; c < 2; c++) {                                 \
        short8 pa_ = lds_ld16((const unsigned short*)(prow + (((4*c + g) ^ l7) << 4))); \
        _Pragma("unroll") for (int n = 0; n < 4; n++)                                 \
          acc_[n] = __builtin_amdgcn_mfma_f32_16x16x32_bf16(pa_, bv[c][n], acc_[n], 0, 0, 0); \
      }                                                                               \
      __builtin_amdgcn_s_setprio(0);                                                  \
    }

    PROCESS_SET(svA, mA, lA, accA, qs0A)
    PROCESS_SET(svB, mB, lB, accB, qs0B)
#undef PROCESS_SET

    // ---- write next tile into the other buffer ----
    if (pf) {
      *reinterpret_cast<uint4*>(&Kl[cur^1][srow0][swz]) = nk0;
      *reinterpret_cast<uint4*>(&Kl[cur^1][srow1][swz]) = nk1;
      *reinterpret_cast<uint4*>(&Vl[cur^1][srow0][swz]) = nv0;
      *reinterpret_cast<uint4*>(&Vl[cur^1][srow1][swz]) = nv1;
    }
    cur ^= 1;
  }

  // ---- finalize both sets: denom = l + 2^(-m) (softmax1) ----
#define FINAL_SET(m_, l_, acc_, qs0_)                                                 \
  {                                                                                   \
    float rs = l_;                                                                    \
    rs += __shfl_xor(rs, 16);                                                         \
    rs += __shfl_xor(rs, 32);                                                         \
    float inv = 1.0f / (rs + exp2f(-m_));                                             \
    _Pragma("unroll") for (int r = 0; r < 4; r++) {                                   \
      float inv4 = __shfl(inv, g*4 + r, 16);                                          \
      int srw = (qs0_) + g*4 + r;                                                     \
      unsigned short* orow = Og + ((size_t)b*S_LEN + srw)*DMODEL + h*HDK;             \
      _Pragma("unroll") for (int n = 0; n < 4; n++)                                   \
        orow[n*16 + lr] = f2bf(acc_[n][r] * inv4);                                    \
    }                                                                                 \
  }
  FINAL_SET(mA, lA, accA, qs0A)
  FINAL_SET(mB, lB, accB, qs0B)
#undef FINAL_SET
}

extern "C" void kernel_launch(void* const* d_in, const int* in_sizes, int n_in,
                              void* d_out, int out_size, void* d_ws, size_t ws_size,
                              hipStream_t stream) {
  const float* hs   = (const float*)d_in[0];
  const float* gate = (const float*)d_in[1];
  const float* lnw  = (const float*)d_in[2];
  const float* qw   = (const float*)d_in[3];
  const float* kw   = (const float*)d_in[4];
  const float* vw   = (const float*)d_in[5];
  const float* ow   = (const float*)d_in[6];
  const float* rel  = (const float*)d_in[7];
  float* out = (float*)d_out;

  char* ws = (char*)d_ws;
  const size_t MB = 1ull << 20;
  unsigned short* xbf  = (unsigned short*)(ws);            // 8 MB  x (bf16)
  unsigned short* wqkv = (unsigned short*)(ws + 8*MB);     // 6 MB  q/k/v weights^T
  unsigned short* wo   = (unsigned short*)(ws + 14*MB);    // 2 MB  o weight^T
  unsigned short* qb   = (unsigned short*)(ws + 16*MB);    // 8 MB  q [BH][S][64] (log2e-scaled)
  unsigned short* kb   = (unsigned short*)(ws + 24*MB);    // 8 MB  k [BH][S][64]
  unsigned short* vt   = (unsigned short*)(ws + 32*MB);    // 8 MB  v^T [B][1024][S]
  unsigned short* ao   = (unsigned short*)(ws + 40*MB);    // 8 MB  attn_out [B][S][1024]
  float*          btab = (float*)(ws + 48*MB);             // 256 KB bias table (log2e-scaled)

  transpose_w_kernel<<<dim3(32,32,4), dim3(32,8), 0, stream>>>(qw, kw, vw, ow, wqkv, wo);
  bias_table_kernel<<<dim3(256), dim3(256), 0, stream>>>(rel, btab);
  rmsnorm_kernel<<<dim3(MTOT), dim3(256), 0, stream>>>(hs, lnw, xbf);
  gemm128<0><<<dim3(MTOT/128, DMODEL/128, 2), dim3(256), 0, stream>>>(
      xbf, wqkv, qb, kb, nullptr, nullptr, nullptr);
  gemm128<2><<<dim3(DMODEL/128, MTOT/128, 1), dim3(256), 0, stream>>>(
      wqkv + (size_t)2*DMODEL*DMODEL, xbf, nullptr, nullptr, vt, nullptr, nullptr);
  attn_kernel<<<dim3(512), dim3(256), 0, stream>>>(
      qb, kb, vt, btab, gate, ao);
  gemm128<1><<<dim3(MTOT/128, DMODEL/128, 1), dim3(256), 0, stream>>>(
      ao, wo, nullptr, nullptr, nullptr, hs, out);
}